// Round 3
// baseline (371.132 us; speedup 1.0000x reference)
//
#include <hip/hip_runtime.h>
#include <hip/hip_bf16.h>

typedef unsigned short u16;
typedef unsigned int u32;
using short8 = __attribute__((ext_vector_type(8))) short;
using f32x4  = __attribute__((ext_vector_type(4))) float;

#define MFMA16(a,b,c) __builtin_amdgcn_mfma_f32_16x16x32_bf16((a),(b),(c),0,0,0)

__device__ __forceinline__ float bf2f(u16 u){
  union { u32 i; float f; } v; v.i = ((u32)u)<<16; return v.f;
}
__device__ __forceinline__ u16 f2bf(float f){
  u32 x = __float_as_uint(f);
  x += 0x7fffu + ((x>>16)&1u);
  return (u16)(x>>16);
}

typedef __attribute__((address_space(1))) const u32 GU32;
typedef __attribute__((address_space(3))) u32 LU32;
__device__ __forceinline__ void gload_lds16(const void* g, void* l){
  __builtin_amdgcn_global_load_lds((GU32*)g, (LU32*)l, 16, 0, 0);
}

// ---------------- fp32 -> bf16 converter ----------------
__global__ __launch_bounds__(256)
void conv_kernel(const float4* __restrict__ in, uint2* __restrict__ out, int n4)
{
  int i = blockIdx.x*256 + threadIdx.x;
  if (i >= n4) return;
  float4 v = in[i];
  union { uint2 u; u16 s[4]; } o;
  o.s[0] = f2bf(v.x); o.s[1] = f2bf(v.y);
  o.s[2] = f2bf(v.z); o.s[3] = f2bf(v.w);
  out[i] = o.u;
}

// ---------------- LayerNorm (+ optional RoPE) ----------------
// one wave per row of 512; 4 rows per block. IN_F32: input dtype fp32 vs bf16.
template<int DO_ROPE, int IN_F32>
__global__ __launch_bounds__(256)
void ln_kernel(const void* __restrict__ inv, const u16* __restrict__ lw,
               const u16* __restrict__ lb, const u16* __restrict__ ct,
               const u16* __restrict__ st, u16* __restrict__ xo,
               u16* __restrict__ xro)
{
  __shared__ float xs[4][512];
  int tid = threadIdx.x, wid = tid>>6, lane = tid&63;
  int m = blockIdx.x*4 + wid;
  int d0 = lane*8;
  float v[8], sum = 0.f, sq = 0.f;
  if (IN_F32){
    const float* in = (const float*)inv;
    float4 a = *(const float4*)(in + (size_t)m*512 + d0);
    float4 b = *(const float4*)(in + (size_t)m*512 + d0 + 4);
    v[0]=a.x; v[1]=a.y; v[2]=a.z; v[3]=a.w;
    v[4]=b.x; v[5]=b.y; v[6]=b.z; v[7]=b.w;
  } else {
    const u16* in = (const u16*)inv;
    union { uint4 q; u16 s[8]; } pk;
    pk.q = *(const uint4*)(in + (size_t)m*512 + d0);
#pragma unroll
    for (int j=0;j<8;j++) v[j] = bf2f(pk.s[j]);
  }
#pragma unroll
  for (int j=0;j<8;j++){ sum+=v[j]; sq+=v[j]*v[j]; }
#pragma unroll
  for (int o=1;o<64;o<<=1){ sum += __shfl_xor(sum,o); sq += __shfl_xor(sq,o); }
  float mean = sum*(1.f/512.f);
  float var  = sq*(1.f/512.f) - mean*mean;
  float rstd = rsqrtf(var + 1e-5f);
  float xn[8];
  union { uint4 q; u16 s[8]; } ou;
#pragma unroll
  for (int j=0;j<8;j++){
    int d = d0+j;
    xn[j] = (v[j]-mean)*rstd*bf2f(lw[d]) + bf2f(lb[d]);
    ou.s[j] = f2bf(xn[j]);
  }
  *(uint4*)(xo + (size_t)m*512 + d0) = ou.q;
  if (DO_ROPE){
#pragma unroll
    for (int j=0;j<8;j++) xs[wid][d0+j] = xn[j];
    __syncthreads();
    int si = m>>1;
    int hb = d0 & ~63;
#pragma unroll
    for (int j=0;j<8;j++){
      int d = d0+j, jh = d&63;
      float rh = (jh<32) ? -xs[wid][hb + 2*jh+1] : xs[wid][hb + 2*(jh-32)];
      float c  = bf2f(ct[si*64+jh]);
      float s2 = bf2f(st[si*64+jh]);
      ou.s[j] = f2bf(xn[j]*c + rh*s2);
    }
    *(uint4*)(xro + (size_t)m*512 + d0) = ou.q;
  }
}

// ---------------- GEMM: C[M,N] = A[M,K] * W[N,K]^T + bias (+epi) ----------------
#define EPI_NONE 0
#define EPI_GELU 1
#define EPI_RES  2

template<int EPI, int RES_F32, int OUT_F32>
__global__ __launch_bounds__(256)
void gemm_bt(const u16* __restrict__ A, const u16* __restrict__ W,
             const u16* __restrict__ bias, const void* __restrict__ resv,
             void* __restrict__ Cv, int M, int N, int K)
{
  __shared__ u16 As[128*32];
  __shared__ u16 Bs[128*32];
  int tid = threadIdx.x, wid = tid>>6, lane = tid&63;
  int l15 = lane & 15, g4 = lane >> 4;
  int nbn = N >> 7;
  int bm = blockIdx.x / nbn, bn = blockIdx.x % nbn;
  int wr = wid >> 1, wc = wid & 1;
  f32x4 acc[4][4];
#pragma unroll
  for (int i=0;i<4;i++)
#pragma unroll
    for (int j=0;j<4;j++) acc[i][j] = (f32x4){0.f,0.f,0.f,0.f};

  const u16* Abase = A + (size_t)(bm*128)*K;
  const u16* Wbase = W + (size_t)(bn*128)*K;
  int rowA = wid*32 + (lane>>2);
  int colA = (lane&3)*8;

  for (int kb = 0; kb < K; kb += 32){
#pragma unroll
    for (int j=0;j<2;j++){
      gload_lds16(Abase + (size_t)(rowA + j*16)*K + kb + colA, &As[(wid*32 + j*16)*32]);
      gload_lds16(Wbase + (size_t)(rowA + j*16)*K + kb + colA, &Bs[(wid*32 + j*16)*32]);
    }
    __syncthreads();
    short8 af[4], bf8[4];
    int ro = 8*g4;
#pragma unroll
    for (int i=0;i<4;i++){
      af[i]  = *(const short8*)&As[(wr*64 + i*16 + l15)*32 + ro];
      bf8[i] = *(const short8*)&Bs[(wc*64 + i*16 + l15)*32 + ro];
    }
#pragma unroll
    for (int i=0;i<4;i++)
#pragma unroll
      for (int j=0;j<4;j++)
        acc[i][j] = MFMA16(af[i], bf8[j], acc[i][j]);
    __syncthreads();
  }
  // epilogue
  int r0 = bm*128 + wr*64 + 4*g4;
  int c0 = bn*128 + wc*64 + l15;
#pragma unroll
  for (int i=0;i<4;i++){
#pragma unroll
    for (int j=0;j<4;j++){
      int col = c0 + j*16;
      float bv = bf2f(bias[col]);
#pragma unroll
      for (int r=0;r<4;r++){
        int row = r0 + i*16 + r;
        size_t idx = (size_t)row*N + col;
        float x = acc[i][j][r] + bv;
        if (EPI == EPI_GELU) x = 0.5f*x*(1.f + erff(x*0.70710678118f));
        if (EPI == EPI_RES){
          if (RES_F32) x += ((const float*)resv)[idx];
          else         x += bf2f(((const u16*)resv)[idx]);
        }
        if (OUT_F32) ((float*)Cv)[idx] = x;
        else         ((u16*)Cv)[idx]   = f2bf(x);
      }
    }
  }
}

// ---------------- Causal flash attention ----------------
__global__ __launch_bounds__(256)
void attn_kernel(const u16* __restrict__ Q, const u16* __restrict__ K,
                 const u16* __restrict__ V, u16* __restrict__ O)
{
  __shared__ u16 Ks[128*72];
  __shared__ u16 Vt[64*136];   // Vt[d][kv], padded
  __shared__ u16 Ps[64*136];
  int tid = threadIdx.x, wid = tid>>6, lane = tid&63;
  int bh = blockIdx.x >> 5, pr = blockIdx.x & 31;
  int b = bh >> 3, h = bh & 7;
  int hoff = b*512 + h*64;
  int l15 = lane & 15, g4 = lane >> 4;

  for (int pass=0; pass<2; ++pass){
    int qt = pass ? (63 - pr) : pr;
    int nkv = (qt>>1) + 1;
    short8 aQ[2];
#pragma unroll
    for (int ks=0; ks<2; ++ks){
      int s = qt*64 + wid*16 + l15;
      aQ[ks] = *(const short8*)(Q + (size_t)s*1024 + hoff + 32*ks + 8*g4);
    }
    f32x4 oacc[4];
#pragma unroll
    for (int fd=0; fd<4; ++fd) oacc[fd] = (f32x4){0.f,0.f,0.f,0.f};
    float mrow[4] = {-1e30f,-1e30f,-1e30f,-1e30f};
    float lrow[4] = {0.f,0.f,0.f,0.f};

    for (int kt=0; kt<nkv; ++kt){
      __syncthreads();
#pragma unroll
      for (int it=0; it<4; ++it){
        int task = it*256 + tid;
        int r = task>>3, cc = (task&7)<<3;
        uint4 g = *(const uint4*)(K + (size_t)(kt*128+r)*1024 + hoff + cc);
        *(uint4*)&Ks[r*72 + cc] = g;
      }
#pragma unroll
      for (int it=0; it<2; ++it){
        int task = it*256 + tid;
        int p = task>>3, cc = (task&7)<<3;
        const u16* vp = V + (size_t)(kt*128 + 2*p)*1024 + hoff + cc;
        union { uint4 q; u16 s[8]; } g0, g1;
        g0.q = *(const uint4*)vp;
        g1.q = *(const uint4*)(vp + 1024);
#pragma unroll
        for (int j=0;j<8;j++){
          int c = cc + j;
          u32 val = (u32)g0.s[j] | ((u32)g1.s[j] << 16);
          *(u32*)&Vt[c*136 + p*2] = val;
        }
      }
      __syncthreads();
      // QK^T
      f32x4 sacc[8];
#pragma unroll
      for (int fk=0; fk<8; ++fk) sacc[fk] = (f32x4){0.f,0.f,0.f,0.f};
#pragma unroll
      for (int ks=0; ks<2; ++ks){
#pragma unroll
        for (int fk=0; fk<8; ++fk){
          short8 bK = *(const short8*)&Ks[(fk*16 + l15)*72 + 32*ks + 8*g4];
          sacc[fk] = MFMA16(aQ[ks], bK, sacc[fk]);
        }
      }
      // online softmax
      int qb0 = qt*64 + wid*16 + 4*g4;
      int kb0 = kt*128 + l15;
      bool diag = (kt == nkv-1);
      float sv[8][4];
      float rowm[4] = {-1e30f,-1e30f,-1e30f,-1e30f};
#pragma unroll
      for (int fk=0; fk<8; ++fk){
#pragma unroll
        for (int j=0;j<4;j++){
          float x = sacc[fk][j]*0.125f;
          if (diag && (kb0 + fk*16 > qb0 + j)) x = -1e30f;
          sv[fk][j] = x;
          rowm[j] = fmaxf(rowm[j], x);
        }
      }
#pragma unroll
      for (int o=1;o<16;o<<=1){
#pragma unroll
        for (int j=0;j<4;j++) rowm[j] = fmaxf(rowm[j], __shfl_xor(rowm[j], o));
      }
      float alpha[4], rsum[4];
#pragma unroll
      for (int j=0;j<4;j++){
        float mn = fmaxf(mrow[j], rowm[j]);
        alpha[j] = __expf(mrow[j]-mn);
        mrow[j] = mn;
        rsum[j] = 0.f;
      }
#pragma unroll
      for (int fk=0; fk<8; ++fk){
#pragma unroll
        for (int j=0;j<4;j++){
          float p = __expf(sv[fk][j]-mrow[j]);
          sv[fk][j] = p;
          rsum[j] += p;
        }
      }
#pragma unroll
      for (int o=1;o<16;o<<=1){
#pragma unroll
        for (int j=0;j<4;j++) rsum[j] += __shfl_xor(rsum[j], o);
      }
#pragma unroll
      for (int j=0;j<4;j++) lrow[j] = lrow[j]*alpha[j] + rsum[j];
#pragma unroll
      for (int fd=0; fd<4; ++fd){
#pragma unroll
        for (int j=0;j<4;j++) oacc[fd][j] *= alpha[j];
      }
      // write P into own wave's LDS region (wave-local)
#pragma unroll
      for (int fk=0; fk<8; ++fk){
#pragma unroll
        for (int j=0;j<4;j++)
          Ps[(wid*16 + 4*g4 + j)*136 + fk*16 + l15] = f2bf(sv[fk][j]);
      }
      // PV
#pragma unroll
      for (int ks=0; ks<4; ++ks){
        short8 aP = *(const short8*)&Ps[(wid*16 + l15)*136 + 32*ks + 8*g4];
#pragma unroll
        for (int fd=0; fd<4; ++fd){
          int d = fd*16 + l15;
          short8 bV = *(const short8*)&Vt[d*136 + 32*ks + 8*g4];
          oacc[fd] = MFMA16(aP, bV, oacc[fd]);
        }
      }
    }
    // epilogue
#pragma unroll
    for (int fd=0; fd<4; ++fd){
#pragma unroll
      for (int j=0;j<4;j++){
        int s = qt*64 + wid*16 + 4*g4 + j;
        float vv = oacc[fd][j] / lrow[j];
        O[(size_t)s*1024 + hoff + fd*16 + l15] = f2bf(vv);
      }
    }
  }
}

// ---------------- launch ----------------
extern "C" void kernel_launch(void* const* d_in, const int* in_sizes, int n_in,
                              void* d_out, int out_size, void* d_ws, size_t ws_size,
                              hipStream_t stream)
{
  float* out = (float*)d_out;                 // reference output dtype: fp32
  const float* src_f = (const float*)d_in[0]; // inputs are fp32
  char* ws = (char*)d_ws;
  const size_t MB = 1024ull*1024ull;
  u16* xbuf = (u16*)(ws);            // [0,8)   LN1 x ; later attn-out
  u16* xr   = (u16*)(ws +  8*MB);    // [8,16)  RoPE(x) ; later src2 (bf16)
  u16* qb   = (u16*)(ws + 16*MB);    // [16,24) Q ; later y2
  u16* kb   = (u16*)(ws + 24*MB);    // [24,32) K
  u16* vb   = (u16*)(ws + 32*MB);    // [32,40) V
  u16* hb   = (u16*)(ws + 24*MB);    // [24,56) FFN hidden (kb,vb dead by then)
  u16* arena= (u16*)(ws + 56*MB);    // ~7.33MB converted bf16 weights/tables
  u16* attn = xbuf;
  u16* src2 = xr;
  u16* y2   = qb;

  // convert inputs 1..14 (weights/tables) fp32 -> bf16
  u16* cv[15];
  cv[0] = nullptr;
  {
    size_t off = 0;
    for (int i=1;i<15;i++){
      cv[i] = arena + off;
      int n = in_sizes[i];
      off += (size_t)n;
      int n4 = n >> 2;
      conv_kernel<<<(n4+255)/256, 256, 0, stream>>>((const float4*)d_in[i], (uint2*)cv[i], n4);
    }
  }
  const u16* rcos = cv[1];
  const u16* rsin = cv[2];
  const u16* inw  = cv[3];
  const u16* inb  = cv[4];
  const u16* outw = cv[5];
  const u16* outb = cv[6];
  const u16* w1   = cv[7];
  const u16* b1   = cv[8];
  const u16* w2   = cv[9];
  const u16* b2   = cv[10];
  const u16* ln1w = cv[11];
  const u16* ln1b = cv[12];
  const u16* ln2w = cv[13];
  const u16* ln2b = cv[14];

  ln_kernel<1,1><<<2048, 256, 0, stream>>>(src_f, ln1w, ln1b, rcos, rsin, xbuf, xr);

  gemm_bt<EPI_NONE,0,0><<<256, 256, 0, stream>>>(xr,   inw,          inb,      nullptr, qb, 8192, 512, 512);
  gemm_bt<EPI_NONE,0,0><<<256, 256, 0, stream>>>(xr,   inw+512*512,  inb+512,  nullptr, kb, 8192, 512, 512);
  gemm_bt<EPI_NONE,0,0><<<256, 256, 0, stream>>>(xbuf, inw+1024*512, inb+1024, nullptr, vb, 8192, 512, 512);

  attn_kernel<<<512, 256, 0, stream>>>(qb, kb, vb, attn);

  // src2 = attn @ outw^T + outb + src   (residual read in fp32)
  gemm_bt<EPI_RES,1,0><<<256, 256, 0, stream>>>(attn, outw, outb, src_f, src2, 8192, 512, 512);

  ln_kernel<0,0><<<2048, 256, 0, stream>>>(src2, ln2w, ln2b, nullptr, nullptr, y2, nullptr);

  gemm_bt<EPI_GELU,0,0><<<1024, 256, 0, stream>>>(y2, w1, b1, nullptr, hb, 8192, 2048, 512);
  // out (fp32) = hb @ w2^T + b2 + src2
  gemm_bt<EPI_RES,0,1><<<256,  256, 0, stream>>>(hb, w2, b2, src2, out, 8192, 512, 2048);
}

// Round 4
// 279.708 us; speedup vs baseline: 1.3269x; 1.3269x over previous
//
#include <hip/hip_runtime.h>
#include <hip/hip_bf16.h>

typedef unsigned short u16;
typedef unsigned int u32;
using short8 = __attribute__((ext_vector_type(8))) short;
using f32x4  = __attribute__((ext_vector_type(4))) float;

#define MFMA16(a,b,c) __builtin_amdgcn_mfma_f32_16x16x32_bf16((a),(b),(c),0,0,0)

__device__ __forceinline__ float bf2f(u16 u){
  union { u32 i; float f; } v; v.i = ((u32)u)<<16; return v.f;
}
__device__ __forceinline__ u16 f2bf(float f){
  u32 x = __float_as_uint(f);
  x += 0x7fffu + ((x>>16)&1u);
  return (u16)(x>>16);
}

typedef __attribute__((address_space(1))) const u32 GU32;
typedef __attribute__((address_space(3))) u32 LU32;
typedef __attribute__((address_space(3))) const u16 LDSU16C;
__device__ __forceinline__ void gload_lds16(const void* g, void* l){
  __builtin_amdgcn_global_load_lds((GU32*)g, (LU32*)l, 16, 0, 0);
}

// hardware transpose read: lane(l15) of each 16-lane group receives column l15
// (4 rows, j=0..3) of the 4x16 bf16 row-major subtile the group addresses.
template<int OFF>
__device__ __forceinline__ uint2 tr16(const u16* p){
  uint2 r;
  if constexpr (OFF == 0)
    asm volatile("ds_read_b64_tr_b16 %0, %1" : "=v"(r) : "v"((LDSU16C*)p));
  else
    asm volatile("ds_read_b64_tr_b16 %0, %1 offset:128" : "=v"(r) : "v"((LDSU16C*)p));
  return r;
}

// ---------------- fused fp32 -> bf16 converter (all weights in 1 launch) ----
struct ConvArgs {
  const float4* in[14];
  uint2* out[14];
  int n4[14];
  int sb[15];   // start block per segment; sb[14] = total blocks
};
__global__ __launch_bounds__(256)
void conv_all(ConvArgs a)
{
  int bid = blockIdx.x;
  int s = 0;
  while (s < 13 && bid >= a.sb[s+1]) ++s;
  int i = (bid - a.sb[s])*256 + threadIdx.x;
  if (i >= a.n4[s]) return;
  float4 v = a.in[s][i];
  union { uint2 u; u16 h[4]; } o;
  o.h[0] = f2bf(v.x); o.h[1] = f2bf(v.y);
  o.h[2] = f2bf(v.z); o.h[3] = f2bf(v.w);
  a.out[s][i] = o.u;
}

// ---------------- LayerNorm (+ optional RoPE) ----------------
template<int DO_ROPE, int IN_F32>
__global__ __launch_bounds__(256)
void ln_kernel(const void* __restrict__ inv, const u16* __restrict__ lw,
               const u16* __restrict__ lb, const u16* __restrict__ ct,
               const u16* __restrict__ st, u16* __restrict__ xo,
               u16* __restrict__ xro)
{
  __shared__ float xs[4][512];
  int tid = threadIdx.x, wid = tid>>6, lane = tid&63;
  int m = blockIdx.x*4 + wid;
  int d0 = lane*8;
  float v[8], sum = 0.f, sq = 0.f;
  if (IN_F32){
    const float* in = (const float*)inv;
    float4 a = *(const float4*)(in + (size_t)m*512 + d0);
    float4 b = *(const float4*)(in + (size_t)m*512 + d0 + 4);
    v[0]=a.x; v[1]=a.y; v[2]=a.z; v[3]=a.w;
    v[4]=b.x; v[5]=b.y; v[6]=b.z; v[7]=b.w;
  } else {
    const u16* in = (const u16*)inv;
    union { uint4 q; u16 s[8]; } pk;
    pk.q = *(const uint4*)(in + (size_t)m*512 + d0);
#pragma unroll
    for (int j=0;j<8;j++) v[j] = bf2f(pk.s[j]);
  }
#pragma unroll
  for (int j=0;j<8;j++){ sum+=v[j]; sq+=v[j]*v[j]; }
#pragma unroll
  for (int o=1;o<64;o<<=1){ sum += __shfl_xor(sum,o); sq += __shfl_xor(sq,o); }
  float mean = sum*(1.f/512.f);
  float var  = sq*(1.f/512.f) - mean*mean;
  float rstd = rsqrtf(var + 1e-5f);
  float xn[8];
  union { uint4 q; u16 s[8]; } ou;
#pragma unroll
  for (int j=0;j<8;j++){
    int d = d0+j;
    xn[j] = (v[j]-mean)*rstd*bf2f(lw[d]) + bf2f(lb[d]);
    ou.s[j] = f2bf(xn[j]);
  }
  *(uint4*)(xo + (size_t)m*512 + d0) = ou.q;
  if (DO_ROPE){
#pragma unroll
    for (int j=0;j<8;j++) xs[wid][d0+j] = xn[j];
    __syncthreads();
    int si = m>>1;
    int hb = d0 & ~63;
#pragma unroll
    for (int j=0;j<8;j++){
      int d = d0+j, jh = d&63;
      float rh = (jh<32) ? -xs[wid][hb + 2*jh+1] : xs[wid][hb + 2*(jh-32)];
      float c  = bf2f(ct[si*64+jh]);
      float s2 = bf2f(st[si*64+jh]);
      ou.s[j] = f2bf(xn[j]*c + rh*s2);
    }
    *(uint4*)(xro + (size_t)m*512 + d0) = ou.q;
  }
}

// ---------------- GEMM: C[M,N] = A[M,K] * W[N,K]^T + bias (+epi) -------------
#define EPI_NONE 0
#define EPI_GELU 1
#define EPI_RES  2

template<int EPI, int RES_F32, int OUT_F32>
__global__ __launch_bounds__(256)
void gemm_bt(const u16* __restrict__ A, const u16* __restrict__ W,
             const u16* __restrict__ bias, const void* __restrict__ resv,
             void* __restrict__ Cv, int M, int N, int K)
{
  __shared__ u16 As[128*32];
  __shared__ u16 Bs[128*32];
  int tid = threadIdx.x, wid = tid>>6, lane = tid&63;
  int l15 = lane & 15, g4 = lane >> 4;
  int nbn = N >> 7;
  int bm = blockIdx.x / nbn, bn = blockIdx.x % nbn;
  int wr = wid >> 1, wc = wid & 1;
  f32x4 acc[4][4];
#pragma unroll
  for (int i=0;i<4;i++)
#pragma unroll
    for (int j=0;j<4;j++) acc[i][j] = (f32x4){0.f,0.f,0.f,0.f};

  const u16* Abase = A + (size_t)(bm*128)*K;
  const u16* Wbase = W + (size_t)(bn*128)*K;
  int rowA = wid*32 + (lane>>2);
  int colA = (lane&3)*8;

  for (int kb = 0; kb < K; kb += 32){
#pragma unroll
    for (int j=0;j<2;j++){
      gload_lds16(Abase + (size_t)(rowA + j*16)*K + kb + colA, &As[(wid*32 + j*16)*32]);
      gload_lds16(Wbase + (size_t)(rowA + j*16)*K + kb + colA, &Bs[(wid*32 + j*16)*32]);
    }
    __syncthreads();
    short8 af[4], bf8[4];
    int ro = 8*g4;
#pragma unroll
    for (int i=0;i<4;i++){
      af[i]  = *(const short8*)&As[(wr*64 + i*16 + l15)*32 + ro];
      bf8[i] = *(const short8*)&Bs[(wc*64 + i*16 + l15)*32 + ro];
    }
#pragma unroll
    for (int i=0;i<4;i++)
#pragma unroll
      for (int j=0;j<4;j++)
        acc[i][j] = MFMA16(af[i], bf8[j], acc[i][j]);
    __syncthreads();
  }
  int r0 = bm*128 + wr*64 + 4*g4;
  int c0 = bn*128 + wc*64 + l15;
#pragma unroll
  for (int i=0;i<4;i++){
#pragma unroll
    for (int j=0;j<4;j++){
      int col = c0 + j*16;
      float bv = bf2f(bias[col]);
#pragma unroll
      for (int r=0;r<4;r++){
        int row = r0 + i*16 + r;
        size_t idx = (size_t)row*N + col;
        float x = acc[i][j][r] + bv;
        if (EPI == EPI_GELU) x = 0.5f*x*(1.f + erff(x*0.70710678118f));
        if (EPI == EPI_RES){
          if (RES_F32) x += ((const float*)resv)[idx];
          else         x += bf2f(((const u16*)resv)[idx]);
        }
        if (OUT_F32) ((float*)Cv)[idx] = x;
        else         ((u16*)Cv)[idx]   = f2bf(x);
      }
    }
  }
}

// ---------------- Causal flash attention (swapped-QK^T, reg-P, tr-read V) ----
// grid 1024: bid>>4 = qt rank (heavy first), bid&15 = (b,h).
// Q/K fused buffer QK[m][1024]: Q cols 0..511, K cols 512..1023, m = s*2+b.
__global__ __launch_bounds__(256, 3)
void attn_kernel(const u16* __restrict__ QK, const u16* __restrict__ V,
                 u16* __restrict__ O)
{
  __shared__ u16 Ks[128*72];        // K rows, +8 pad
  __shared__ u16 Vp[4*2064];        // 4 panels [128 kv][16 d] +16 pad each
  int tid = threadIdx.x, wid = tid>>6, lane = tid&63;
  int l15 = lane&15, g4 = lane>>4;
  int qt = 63 - (blockIdx.x >> 4);
  int bh = blockIdx.x & 15;
  int b = bh>>3, h = bh&7;
  int nkv = (qt>>1) + 1;
  size_t qkbh = (size_t)b*1024 + h*64;   // + s*2048 (+512 for K)
  size_t vbh  = (size_t)b*512  + h*64;   // + s*1024

  // Q as B-fragment: col=q-row (l15), k = 32ks+8g4+j
  short8 aQ[2];
  {
    int s = qt*64 + wid*16 + l15;
#pragma unroll
    for (int ks=0; ks<2; ++ks)
      aQ[ks] = *(const short8*)(QK + (size_t)s*2048 + qkbh + 32*ks + 8*g4);
  }
  f32x4 oacc[4];
#pragma unroll
  for (int fd=0; fd<4; ++fd) oacc[fd] = (f32x4){0.f,0.f,0.f,0.f};
  float mrun = -1e30f, lrun = 0.f;
  int q_abs = qt*64 + wid*16 + l15;

  for (int kt=0; kt<nkv; ++kt){
    __syncthreads();
    // stage K tile [128][64] -> Ks[128][72]
#pragma unroll
    for (int it=0; it<4; ++it){
      int task = it*256 + tid, r = task>>3, cc = (task&7)<<3;
      uint4 g = *(const uint4*)(QK + (size_t)(kt*128+r)*2048 + qkbh + 512 + cc);
      *(uint4*)&Ks[r*72 + cc] = g;
    }
    // stage V tile row-major into 4 d-panels (conflict-free b128 writes)
#pragma unroll
    for (int it=0; it<4; ++it){
      int task = it*256 + tid, r = task>>3, cc = (task&7)<<3;
      uint4 g = *(const uint4*)(V + (size_t)(kt*128+r)*1024 + vbh + cc);
      int fd = cc>>4, dd = cc&15;
      *(uint4*)&Vp[fd*2064 + r*16 + dd] = g;
    }
    __syncthreads();

    // S^T = K @ Q^T : lane holds q = l15, kv = 16fk + 4g4 + reg
    f32x4 sacc[8];
#pragma unroll
    for (int fk=0; fk<8; ++fk) sacc[fk] = (f32x4){0.f,0.f,0.f,0.f};
#pragma unroll
    for (int ks=0; ks<2; ++ks)
#pragma unroll
      for (int fk=0; fk<8; ++fk){
        short8 aK = *(const short8*)&Ks[(fk*16 + l15)*72 + 32*ks + 8*g4];
        sacc[fk] = MFMA16(aK, aQ[ks], sacc[fk]);
      }

    // per-lane online softmax over own 32 kv values
    bool maskt = (kt == nkv-1);
    int kvb = kt*128 + 4*g4;
    float p[8][4];
    float pmax = -1e30f;
#pragma unroll
    for (int fk=0; fk<8; ++fk)
#pragma unroll
      for (int r=0;r<4;r++){
        float x = sacc[fk][r]*0.125f;
        if (maskt && (kvb + 16*fk + r > q_abs)) x = -1e30f;
        p[fk][r] = x;
        pmax = fmaxf(pmax, x);
      }
    pmax = fmaxf(pmax, __shfl_xor(pmax,16));
    pmax = fmaxf(pmax, __shfl_xor(pmax,32));
    float mn = fmaxf(mrun, pmax);
    float alpha = __expf(mrun - mn);
    mrun = mn;
    float ps = 0.f;
#pragma unroll
    for (int fk=0; fk<8; ++fk)
#pragma unroll
      for (int r=0;r<4;r++){ float e = __expf(p[fk][r]-mn); p[fk][r]=e; ps += e; }
    ps += __shfl_xor(ps,16);
    ps += __shfl_xor(ps,32);
    lrun = lrun*alpha + ps;

    // rescale O (rows q = 4g4+reg -> fetch alpha from lane l15 = 4g4+reg)
    float alr[4];
#pragma unroll
    for (int r=0;r<4;r++) alr[r] = __shfl(alpha, 20*g4 + r);
#pragma unroll
    for (int fd=0; fd<4; ++fd)
#pragma unroll
      for (int r=0;r<4;r++) oacc[fd][r] *= alr[r];

    // pack P to bf16 pairs: pv[fk][t] = (P[16fk+4g4+2t], P[+1])
    u32 pv[8][2];
#pragma unroll
    for (int fk=0;fk<8;++fk)
#pragma unroll
      for (int t=0;t<2;++t)
        pv[fk][t] = (u32)f2bf(p[fk][2*t]) | ((u32)f2bf(p[fk][2*t+1])<<16);

    // PV: A-frag from shuffled pv, B-frag via hardware transpose-read of Vp
    int hi = g4>>1, lo2 = (g4&1)*2;
#pragma unroll
    for (int ks=0; ks<4; ++ks){
      union { u32 w[4]; short8 s8; } pa;
#pragma unroll
      for (int w=0; w<4; ++w){
        int srcLane = 16*(lo2 + (w>>1)) + l15;
        u32 a0 = __shfl(pv[2*ks  ][w&1], srcLane);
        u32 a1 = __shfl(pv[2*ks+1][w&1], srcLane);
        pa.w[w] = hi ? a1 : a0;
      }
      union { uint2 u2[2]; short8 s8; } bv[4];
#pragma unroll
      for (int fd=0; fd<4; ++fd){
        const u16* base = &Vp[fd*2064 + (32*ks + 8*g4)*16 + l15*4];
        bv[fd].u2[0] = tr16<0>(base);
        bv[fd].u2[1] = tr16<128>(base);
      }
      asm volatile("s_waitcnt lgkmcnt(0)");
      __builtin_amdgcn_sched_barrier(0);
#pragma unroll
      for (int fd=0; fd<4; ++fd)
        oacc[fd] = MFMA16(pa.s8, bv[fd].s8, oacc[fd]);
    }
  }
  // epilogue: O[q = 4g4+reg][d = 16fd + l15]
  float lr[4];
#pragma unroll
  for (int r=0;r<4;r++) lr[r] = __shfl(lrun, 20*g4 + r);
#pragma unroll
  for (int fd=0; fd<4; ++fd)
#pragma unroll
    for (int r=0;r<4;r++){
      int s = qt*64 + wid*16 + 4*g4 + r;
      O[(size_t)s*1024 + vbh + fd*16 + l15] = f2bf(oacc[fd][r]/lr[r]);
    }
}

// ---------------- launch ----------------
extern "C" void kernel_launch(void* const* d_in, const int* in_sizes, int n_in,
                              void* d_out, int out_size, void* d_ws, size_t ws_size,
                              hipStream_t stream)
{
  float* out = (float*)d_out;                 // output fp32
  const float* src_f = (const float*)d_in[0]; // inputs fp32
  char* ws = (char*)d_ws;
  const size_t MB = 1024ull*1024ull;
  u16* xbuf = (u16*)(ws);            // [0,8)   x ; later attn-out
  u16* xr   = (u16*)(ws +  8*MB);    // [8,16)  RoPE(x) ; later src2
  u16* qk   = (u16*)(ws + 16*MB);    // [16,32) fused Q|K ; later y2 [16,24)
  u16* vb   = (u16*)(ws + 32*MB);    // [32,40) V
  u16* hb   = (u16*)(ws + 24*MB);    // [24,56) FFN hidden (qk/vb dead then)
  u16* arena= (u16*)(ws + 56*MB);    // ~7.35MB converted bf16 weights
  u16* attn = xbuf;
  u16* src2 = xr;
  u16* y2   = qk;

  // fused convert of inputs 1..14
  ConvArgs ca;
  u16* cv[15]; cv[0] = nullptr;
  {
    size_t off = 0; int blk = 0;
    for (int i=1;i<15;i++){
      cv[i] = arena + off;
      int n = in_sizes[i];
      ca.in[i-1]  = (const float4*)d_in[i];
      ca.out[i-1] = (uint2*)cv[i];
      ca.n4[i-1]  = n >> 2;
      ca.sb[i-1]  = blk;
      blk += ((n>>2) + 255) / 256;
      off += (size_t)n;
    }
    ca.sb[14] = blk;
    conv_all<<<blk, 256, 0, stream>>>(ca);
  }
  const u16* rcos = cv[1];
  const u16* rsin = cv[2];
  const u16* inw  = cv[3];
  const u16* inb  = cv[4];
  const u16* outw = cv[5];
  const u16* outb = cv[6];
  const u16* w1   = cv[7];
  const u16* b1   = cv[8];
  const u16* w2   = cv[9];
  const u16* b2   = cv[10];
  const u16* ln1w = cv[11];
  const u16* ln1b = cv[12];
  const u16* ln2w = cv[13];
  const u16* ln2b = cv[14];

  ln_kernel<1,1><<<2048, 256, 0, stream>>>(src_f, ln1w, ln1b, rcos, rsin, xbuf, xr);

  // fused Q|K projection (A = xr for both): N = 1024
  gemm_bt<EPI_NONE,0,0><<<512, 256, 0, stream>>>(xr,   inw,          inb,      nullptr, qk, 8192, 1024, 512);
  gemm_bt<EPI_NONE,0,0><<<256, 256, 0, stream>>>(xbuf, inw+1024*512, inb+1024, nullptr, vb, 8192,  512, 512);

  attn_kernel<<<1024, 256, 0, stream>>>(qk, vb, attn);

  gemm_bt<EPI_RES,1,0><<<256, 256, 0, stream>>>(attn, outw, outb, src_f, src2, 8192, 512, 512);

  ln_kernel<0,0><<<2048, 256, 0, stream>>>(src2, ln2w, ln2b, nullptr, nullptr, y2, nullptr);

  gemm_bt<EPI_GELU,0,0><<<1024, 256, 0, stream>>>(y2, w1, b1, nullptr, hb, 8192, 2048, 512);
  gemm_bt<EPI_RES,0,1><<<256,  256, 0, stream>>>(hb, w2, b2, src2, out, 8192, 512, 2048);
}